// Round 6
// baseline (270.745 us; speedup 1.0000x reference)
//
#include <hip/hip_runtime.h>

// Fused MSE + SSIM loss, 32x3x512x512 fp32, MI355X.
// R5b: both 11-tap gaussian passes as band-matrix MFMA (mfma_f32_16x16x32_bf16).
//   horizontal: A = field data (global->reg, bf16), B = band w[c-x-3], per
//     (xblk 0..3, rowblk 0..2) job; D = 4 rows/lane -> ds_write_b64 to x-major HP.
//   vertical:   A = band w[k-m], B = HP 8-consecutive-row b128 reads, per
//     (yblk 0..1, xblk 0..3) job; D = 4 px/lane -> fp32 SSIM math.
// Tile 64x32, 256 thr (4 waves: 3 horiz jobs + 2 vert jobs each).
// LDS 31 KB -> 5 blocks/CU. Pad rows 42..47 = finite garbage x zero band weight.

#define WSZ   512
#define TW    64
#define TH    32
#define PITCH 48               // HP row-dim allocation (x-major), rows 0..47
#define NSLOT 64
#define SSIM_C1 0.0001f
#define SSIM_C2 0.0009f

__device__ __constant__ float GW[11] = {
    0.00102838f, 0.00759876f, 0.03600080f, 0.10936080f, 0.21300560f,
    0.26601170f,
    0.21300560f, 0.10936080f, 0.03600080f, 0.00759876f, 0.00102838f};

typedef __attribute__((ext_vector_type(8))) short short8;
typedef __attribute__((ext_vector_type(4))) float f32x4;

// branch-free RNE fp32 -> bf16 (inputs here are finite; no NaN handling needed)
static __device__ __forceinline__ unsigned int bf16r(float x) {
    const unsigned int u = __builtin_bit_cast(unsigned int, x);
    return (u + 0x7FFFu + ((u >> 16) & 1u)) >> 16;
}
static __device__ __forceinline__ unsigned int pkbf(float a, float b) {
    return bf16r(a) | (bf16r(b) << 16);
}

static __device__ __forceinline__ short8 mkfrag(const float v[8]) {
    uint4 u;
    u.x = pkbf(v[0], v[1]);
    u.y = pkbf(v[2], v[3]);
    u.z = pkbf(v[4], v[5]);
    u.w = pkbf(v[6], v[7]);
    return __builtin_bit_cast(short8, u);
}

__launch_bounds__(256, 5)
__global__ void fused_mse_ssim(const float* __restrict__ P,
                               const float* __restrict__ T,
                               float* __restrict__ ws) {
    __shared__ unsigned short sHP[5][64 * PITCH];   // 30720 B, x-major [x][row]
    __shared__ float sEXT[72];                      // extended band weights
    __shared__ float red[2][4];

    const int tid  = threadIdx.x;
    const int wave = tid >> 6;
    const int lane = tid & 63;
    const int q    = lane >> 4;      // quad
    const int n15  = lane & 15;
    const int gx0  = blockIdx.x * TW;
    const int gy0  = blockIdx.y * TH;
    const size_t plane = (size_t)blockIdx.z * (WSZ * (size_t)WSZ);
    const float* Pp = P + plane;
    const float* Tp = T + plane;

    // extended weight table: EXT[i] = w[i-32] for i in [32,42], else 0
    if (tid < 72) {
        const int i = tid - 32;
        sEXT[tid] = ((unsigned)i < 11u) ? GW[i] : 0.f;
    }

    // ---- MSE partial: 8 px/thread, coalesced float4 (also warms L1/L2) ----
    float mse = 0.f;
    {
        const int r = tid >> 3;            // 0..31
        const int x = (tid & 7) * 8;       // 0..56
        const float* pr = Pp + (size_t)(gy0 + r) * WSZ + gx0 + x;
        const float* tr = Tp + (size_t)(gy0 + r) * WSZ + gx0 + x;
        #pragma unroll
        for (int h = 0; h < 2; ++h) {
            const float4 pv = *(const float4*)(pr + h * 4);
            const float4 tv = *(const float4*)(tr + h * 4);
            float d;
            d = pv.x - tv.x; mse = fmaf(d, d, mse);
            d = pv.y - tv.y; mse = fmaf(d, d, mse);
            d = pv.z - tv.z; mse = fmaf(d, d, mse);
            d = pv.w - tv.w; mse = fmaf(d, d, mse);
        }
    }
    __syncthreads();    // sEXT ready

    // ---- band fragments (constant per lane) ----
    // horizontal B-operand: B[k=8q+j][n=n15] = w[k - n15 - 3] = EXT[29 + 8q - n15 + j]
    // vertical   A-operand: A[m=n15][k=8q+j] = w[k - n15]     = EXT[32 + 8q - n15 + j]
    short8 bandH, bandV;
    {
        float vh[8], vv[8];
        const int sH = 29 + q * 8 - n15;
        const int sV = 32 + q * 8 - n15;
        #pragma unroll
        for (int j = 0; j < 8; ++j) { vh[j] = sEXT[sH + j]; vv[j] = sEXT[sV + j]; }
        bandH = mkfrag(vh);
        bandV = mkfrag(vv);
    }
    const f32x4 zero4 = {0.f, 0.f, 0.f, 0.f};

    // ---- stage A: horizontal pass. 12 jobs (b=xblk 0..3, rb=rowblk 0..2) ----
    #pragma unroll
    for (int jj = 0; jj < 3; ++jj) {
        const int job = wave + jj * 4;
        const int b  = job & 3;
        const int rb = job >> 2;
        const int hr   = rb * 16 + n15;          // halo row 0..47 (valid < 42)
        const int grow = gy0 - 5 + hr;
        const bool rowok = ((unsigned)grow < (unsigned)WSZ);
        const int growc = min(max(grow, 0), WSZ - 1);
        const int c0 = gx0 - 8 + b * 16 + q * 8; // 8 cols, 16B-aligned blocks
        const float* prow = Pp + (size_t)growc * WSZ;
        const float* trow = Tp + (size_t)growc * WSZ;

        float4 pa = make_float4(0.f,0.f,0.f,0.f), pb = pa, ta = pa, tb = pa;
        if ((unsigned)c0 < (unsigned)WSZ)       { pa = *(const float4*)(prow + c0);     ta = *(const float4*)(trow + c0); }
        if ((unsigned)(c0 + 4) < (unsigned)WSZ) { pb = *(const float4*)(prow + c0 + 4); tb = *(const float4*)(trow + c0 + 4); }

        float p[8] = {pa.x, pa.y, pa.z, pa.w, pb.x, pb.y, pb.z, pb.w};
        float t[8] = {ta.x, ta.y, ta.z, ta.w, tb.x, tb.y, tb.z, tb.w};
        if (!rowok) {
            #pragma unroll
            for (int i = 0; i < 8; ++i) { p[i] = 0.f; t[i] = 0.f; }
        }
        float pp[8], tt[8], pt[8];
        #pragma unroll
        for (int i = 0; i < 8; ++i) {
            pp[i] = p[i] * p[i];
            tt[i] = t[i] * t[i];
            pt[i] = p[i] * t[i];
        }
        const short8 fP  = mkfrag(p);
        const short8 fT  = mkfrag(t);
        const short8 fPP = mkfrag(pp);
        const short8 fTT = mkfrag(tt);
        const short8 fPT = mkfrag(pt);

        const f32x4 dP  = __builtin_amdgcn_mfma_f32_16x16x32_bf16(fP,  bandH, zero4, 0, 0, 0);
        const f32x4 dT  = __builtin_amdgcn_mfma_f32_16x16x32_bf16(fT,  bandH, zero4, 0, 0, 0);
        const f32x4 dPP = __builtin_amdgcn_mfma_f32_16x16x32_bf16(fPP, bandH, zero4, 0, 0, 0);
        const f32x4 dTT = __builtin_amdgcn_mfma_f32_16x16x32_bf16(fTT, bandH, zero4, 0, 0, 0);
        const f32x4 dPT = __builtin_amdgcn_mfma_f32_16x16x32_bf16(fPT, bandH, zero4, 0, 0, 0);

        // lane holds out_h[rows rb*16+4q+0..3][x = b*16+n15]
        const int off = (b * 16 + n15) * PITCH + rb * 16 + q * 4;
        *(uint2*)&sHP[0][off] = make_uint2(pkbf(dP[0],  dP[1]),  pkbf(dP[2],  dP[3]));
        *(uint2*)&sHP[1][off] = make_uint2(pkbf(dT[0],  dT[1]),  pkbf(dT[2],  dT[3]));
        *(uint2*)&sHP[2][off] = make_uint2(pkbf(dPP[0], dPP[1]), pkbf(dPP[2], dPP[3]));
        *(uint2*)&sHP[3][off] = make_uint2(pkbf(dTT[0], dTT[1]), pkbf(dTT[2], dTT[3]));
        *(uint2*)&sHP[4][off] = make_uint2(pkbf(dPT[0], dPT[1]), pkbf(dPT[2], dPT[3]));
    }
    __syncthreads();

    // ---- stage B: vertical pass + SSIM. 8 jobs (yb 0..1, xb 0..3) ----
    float ssim = 0.f;
    #pragma unroll
    for (int jj = 0; jj < 2; ++jj) {
        const int job = wave + jj * 4;
        const int yb = job >> 2;
        const int xb = job & 3;
        const int off = (xb * 16 + n15) * PITCH + yb * 16 + q * 8;  // 8 consecutive rows
        f32x4 d[5];
        #pragma unroll
        for (int f = 0; f < 5; ++f) {
            const short8 bf = *(const short8*)&sHP[f][off];
            d[f] = __builtin_amdgcn_mfma_f32_16x16x32_bf16(bandV, bf, zero4, 0, 0, 0);
        }
        #pragma unroll
        for (int r = 0; r < 4; ++r) {
            const float mu1 = d[0][r];
            const float mu2 = d[1][r];
            const float vpp = d[2][r];
            const float vtt = d[3][r];
            const float vpt = d[4][r];
            const float mu1sq = mu1 * mu1;
            const float mu2sq = mu2 * mu2;
            const float mu12  = mu1 * mu2;
            const float s1  = vpp - mu1sq;
            const float s2  = vtt - mu2sq;
            const float s12 = vpt - mu12;
            const float num = fmaf(2.f, mu12, SSIM_C1) * fmaf(2.f, s12, SSIM_C2);
            const float den = (mu1sq + mu2sq + SSIM_C1) * (s1 + s2 + SSIM_C2);
            ssim = fmaf(num, __builtin_amdgcn_rcpf(den), ssim);
        }
    }

    // ---- reduction: wave shuffle -> LDS -> spread atomics ----
    #pragma unroll
    for (int off = 32; off > 0; off >>= 1) {
        mse  += __shfl_down(mse, off);
        ssim += __shfl_down(ssim, off);
    }
    if ((tid & 63) == 0) { red[0][wave] = mse; red[1][wave] = ssim; }
    __syncthreads();
    if (tid == 0) {
        const float m = red[0][0] + red[0][1] + red[0][2] + red[0][3];
        const float s = red[1][0] + red[1][1] + red[1][2] + red[1][3];
        const int bid  = (blockIdx.z * gridDim.y + blockIdx.y) * gridDim.x + blockIdx.x;
        const int slot = (bid & (NSLOT - 1)) * 16;   // 64B apart
        atomicAdd(&ws[slot + 0], m);
        atomicAdd(&ws[slot + 1], s);
    }
}

__global__ void finalize_loss(const float* __restrict__ ws,
                              float* __restrict__ out, float invN) {
    const int t = threadIdx.x;           // 64 threads
    float m = ws[t * 16 + 0];
    float s = ws[t * 16 + 1];
    #pragma unroll
    for (int off = 32; off > 0; off >>= 1) {
        m += __shfl_down(m, off);
        s += __shfl_down(s, off);
    }
    if (t == 0) out[0] = m * invN + 0.01f * (1.f - s * invN);
}

extern "C" void kernel_launch(void* const* d_in, const int* in_sizes, int n_in,
                              void* d_out, int out_size, void* d_ws, size_t ws_size,
                              hipStream_t stream) {
    const float* P = (const float*)d_in[0];
    const float* T = (const float*)d_in[1];
    float* out = (float*)d_out;
    float* ws  = (float*)d_ws;

    const int planes = in_sizes[0] / (WSZ * WSZ);     // 96
    const float invN = 1.f / (float)in_sizes[0];

    (void)hipMemsetAsync(ws, 0, NSLOT * 16 * sizeof(float), stream);
    dim3 grid(WSZ / TW, WSZ / TH, planes);
    fused_mse_ssim<<<grid, 256, 0, stream>>>(P, T, ws);
    finalize_loss<<<1, 64, 0, stream>>>(ws, out, invN);
}